// Round 1
// baseline (328.513 us; speedup 1.0000x reference)
//
#include <hip/hip_runtime.h>

#define IMG_H 512
#define IMG_W 512
#define TILE_W 64
#define TILE_H 16
#define LDSW 72   // 64 + 8 halo/alignment cols (covers x0-4 .. x0+67)
#define LDSH 22   // 16 + 6 halo rows (covers y0-3 .. y0+18)
#define TCOLS 72  // intermediate planes: 16 rows x 72 cols
#define TROWS 16
#define NTHREADS 256

// ---------------- compile-time coefficient generation --------------------
// All filter kernels are input-independent: evaluated at COMPILE TIME in
// double precision (constexpr Taylor exp/cos/sin). The filter bank is
// decomposed into SEPARABLE rank-1/rank-2 terms:
//   log5/log7 : LoG = (-c*g + c'*y^2 g) (x) g  +  g (x) (c'*x^2 g)   [rank 2]
//   hpf5      : 25*center - box5,  box5 = ones (x) ones              [rank 1]
//   gab0      : gauss(y) (x) [gauss*cos(w0 x)]                       [rank 1]
//   gab90     : [gauss*cos(w0 y)] (x) gauss                          [rank 1]
//   gab45/135 : share P = gc(y)(x)gc(x), Q = gs(y)(x)gs(x);
//               gab45 = (P-Q)/s45, gab135 = (P+Q)/s135               [rank 2]
//   3x3 (lpf/log3/hpf3): direct via D4 symmetry class sums (m, e, s)
// This cuts per-pixel MACs 322 -> ~150.

constexpr double PI_D = 3.141592653589793238462643383279502884;

constexpr double cexp(double x) {
  double term = 1.0, sum = 1.0;
  for (int n = 1; n < 48; ++n) { term *= x / n; sum += term; }
  return sum;
}
constexpr double ccos(double x) {
  double term = 1.0, sum = 1.0;
  for (int n = 1; n < 24; ++n) {
    term *= -x * x / ((2.0 * n - 1.0) * (2.0 * n));
    sum += term;
  }
  return sum;
}
constexpr double csin(double x) {
  double term = x, sum = x;
  for (int n = 1; n < 24; ++n) {
    term *= -x * x / ((2.0 * n) * (2.0 * n + 1.0));
    sum += term;
  }
  return sum;
}
constexpr double cabs_(double x) { return x < 0 ? -x : x; }

constexpr void fill_log(int ks, double sigma, float* out) {
  double buf[49] = {};
  double s = 0.0;
  const int h = ks / 2;
  for (int i = 0; i < ks; ++i) {
    for (int j = 0; j < ks; ++j) {
      const double xi = (double)(i - h);
      const double yj = (double)(j - h);
      const double r2 = xi * xi + yj * yj;
      const double g = cexp(-r2 / (2.0 * sigma * sigma));
      const double lap = -1.0 / (PI_D * sigma * sigma * sigma * sigma) *
                         (1.0 - r2 / (2.0 * sigma * sigma));
      buf[i * ks + j] = lap * g;
      s += cabs_(lap * g);
    }
  }
  for (int k = 0; k < ks * ks; ++k) out[k] = (float)(buf[k] / s);
}

// separable LoG factors: k/s = va (x) g  +  g (x) wb
constexpr void fill_log_sep(int ks, double sigma, float* va, float* g, float* wb) {
  const int h = ks / 2;
  double s = 0.0;
  for (int i = 0; i < ks; ++i)
    for (int j = 0; j < ks; ++j) {
      const double xi = (double)(i - h), yj = (double)(j - h);
      const double r2 = xi * xi + yj * yj;
      const double gg = cexp(-r2 / (2.0 * sigma * sigma));
      const double lap = -1.0 / (PI_D * sigma * sigma * sigma * sigma) *
                         (1.0 - r2 / (2.0 * sigma * sigma));
      s += cabs_(lap * gg);
    }
  const double c = 1.0 / (PI_D * sigma * sigma * sigma * sigma);
  for (int i = 0; i < ks; ++i) {
    const double d = (double)(i - h);
    const double gi = cexp(-d * d / (2.0 * sigma * sigma));
    g[i] = (float)gi;
    va[i] = (float)((-c + c * d * d / (2.0 * sigma * sigma)) * gi / s);
    wb[i] = (float)((c * d * d / (2.0 * sigma * sigma)) * gi / s);
  }
}

constexpr double gabor_norm(double ang_deg) {
  const double th = ang_deg * PI_D / 180.0;
  const double ct = ccos(th), st = csin(th);
  double s = 0.0;
  for (int i = 0; i < 7; ++i)
    for (int j = 0; j < 7; ++j) {
      const double xv = (double)(j - 3);
      const double yv = (double)(i - 3);
      const double xt = xv * ct + yv * st;
      const double yt = -xv * st + yv * ct;
      const double g = cexp(-(xt * xt / 4.0 + yt * yt / 4.0) / 2.0) *
                       ccos(2.0 * PI_D * 0.1 * xt);
      s += cabs_(g);
    }
  return s;
}

struct SepTabs {
  float l5_va[5], l5_g[5], l5_wb[5];
  float l7_va[7], l7_g[7], l7_wb[7];
  float v_gb[7], v_gc0[7], v_gca[7], v_gsa[7];   // vertical (stage A)
  float h_g0[7], h_g90[7], h_gc[7], h_gs[7];     // horizontal (stage B)
  float is45, is135;
  float l3_m, l3_e, l3_s;                        // log3 symmetry classes
};

constexpr SepTabs make_sep() {
  SepTabs t{};
  fill_log_sep(5, 1.0, t.l5_va, t.l5_g, t.l5_wb);
  fill_log_sep(7, 1.4, t.l7_va, t.l7_g, t.l7_wb);
  const double s0 = gabor_norm(0.0), s90 = gabor_norm(90.0);
  const double s45 = gabor_norm(45.0), s135 = gabor_norm(135.0);
  const double th45 = 45.0 * PI_D / 180.0;
  const double a45 = 2.0 * PI_D * 0.1 * ccos(th45);  // x (horizontal) freq
  const double b45 = 2.0 * PI_D * 0.1 * csin(th45);  // y (vertical) freq
  const double w0 = 2.0 * PI_D * 0.1;
  for (int k = 0; k < 7; ++k) {
    const double d = (double)(k - 3);
    const double gg = cexp(-d * d / 8.0);            // sigma = 2
    t.v_gb[k]  = (float)gg;                          // gab0 vertical
    t.v_gc0[k] = (float)(gg * ccos(w0 * d));         // gab90 vertical
    t.v_gca[k] = (float)(gg * ccos(b45 * d));        // 45/135 vertical (cos)
    t.v_gsa[k] = (float)(gg * csin(b45 * d));        // 45/135 vertical (sin)
    t.h_g0[k]  = (float)(gg * ccos(w0 * d) / s0);    // gab0 horizontal
    t.h_g90[k] = (float)(gg / s90);                  // gab90 horizontal
    t.h_gc[k]  = (float)(gg * ccos(a45 * d));        // 45/135 horizontal (cos)
    t.h_gs[k]  = (float)(gg * csin(a45 * d));        // 45/135 horizontal (sin)
  }
  t.is45 = (float)(1.0 / s45);
  t.is135 = (float)(1.0 / s135);
  float l3[9] = {};
  fill_log(3, 0.8, l3);
  t.l3_m = l3[4]; t.l3_e = l3[1]; t.l3_s = l3[0];
  return t;
}

constexpr SepTabs ST = make_sep();

// ------------------------------- kernel ----------------------------------

__device__ __forceinline__ float fast_tanh(float x) {
  float e = __builtin_amdgcn_exp2f(x * 2.8853900817779268f);
  return 1.0f - 2.0f * __builtin_amdgcn_rcpf(e + 1.0f);
}
__device__ __forceinline__ float squash_from(float z) {
  return fmaf(fast_tanh(0.1f * z), 0.5f, 0.5f);
}
__device__ __forceinline__ float4 f4z() { return make_float4(0.f, 0.f, 0.f, 0.f); }
__device__ __forceinline__ float4 f4add(float4 a, float4 b) {
  return make_float4(a.x + b.x, a.y + b.y, a.z + b.z, a.w + b.w);
}
__device__ __forceinline__ float4 f4fma(float a, float4 b, float4 c) {
  return make_float4(fmaf(a, b.x, c.x), fmaf(a, b.y, c.y),
                     fmaf(a, b.z, c.z), fmaf(a, b.w, c.w));
}
__device__ __forceinline__ void loadw12(const float* p, float* w) {
  const float4 a = *(const float4*)(p);
  const float4 b = *(const float4*)(p + 4);
  const float4 c = *(const float4*)(p + 8);
  w[0] = a.x; w[1] = a.y; w[2] = a.z; w[3] = a.w;
  w[4] = b.x; w[5] = b.y; w[6] = b.z; w[7] = b.w;
  w[8] = c.x; w[9] = c.y; w[10] = c.z; w[11] = c.w;
}

// intermediate plane indices
#define T_B5  0
#define T_L5A 1
#define T_L5G 2
#define T_L7A 3
#define T_L7G 4
#define T_GB  5
#define T_GC0 6
#define T_GCA 7
#define T_GSA 8

__global__ __launch_bounds__(NTHREADS)
void msif_kernel(const float* __restrict__ x, float* __restrict__ out,
                 int planes, int do_gab) {
  __shared__ float tile[LDSH * LDSW];
  __shared__ float T[9][TROWS * TCOLS];   // 41472 B; total LDS 47808 B -> 3 blk/CU

  const int tid = threadIdx.x;
  const int tx = tid & 15;   // 16 threads wide, 4 px each -> 64 cols
  const int ty = tid >> 4;   // 16 rows, 1 px each
  const int x0 = blockIdx.x * TILE_W;
  const int y0 = blockIdx.y * TILE_H;
  const int plane = blockIdx.z;
  const float* __restrict__ in = x + (size_t)plane * (IMG_H * IMG_W);

  // ---- stage input tile (zero padded at borders) ----
  const int gx0 = x0 - 4;
  const int gy0 = y0 - 3;
  for (int k = tid; k < LDSH * (LDSW / 4); k += NTHREADS) {
    int r = k / (LDSW / 4);
    int cc = (k - r * (LDSW / 4)) * 4;
    int gy = gy0 + r;
    int gx = gx0 + cc;
    float4 v = make_float4(0.f, 0.f, 0.f, 0.f);
    if ((unsigned)gy < IMG_H) {
      const float* rowp = in + (size_t)gy * IMG_W;
      if (gx >= 0 && gx + 3 < IMG_W) {
        v = *(const float4*)(rowp + gx);
      } else {
        float t0 = 0.f, t1 = 0.f, t2 = 0.f, t3 = 0.f;
        if ((unsigned)(gx + 0) < IMG_W) t0 = rowp[gx + 0];
        if ((unsigned)(gx + 1) < IMG_W) t1 = rowp[gx + 1];
        if ((unsigned)(gx + 2) < IMG_W) t2 = rowp[gx + 2];
        if ((unsigned)(gx + 3) < IMG_W) t3 = rowp[gx + 3];
        v = make_float4(t0, t1, t2, t3);
      }
    }
    *(float4*)&tile[r * LDSW + cc] = v;
  }
  __syncthreads();

  // ---- stage A: vertical passes over all 72 halo columns, 16 out rows ----
  for (int k = tid; k < TROWS * (TCOLS / 4); k += NTHREADS) {  // 288 f4 slots
    const int r = k / (TCOLS / 4);
    const int c4 = (k - r * (TCOLS / 4)) * 4;
    const float* base = &tile[r * LDSW + c4];
    float4 wv[7];
#pragma unroll
    for (int i = 0; i < 7; ++i) wv[i] = *(const float4*)(base + i * LDSW);

    float4 b5 = f4add(f4add(wv[1], wv[2]), f4add(f4add(wv[3], wv[4]), wv[5]));
    float4 l5a = f4z(), l5g = f4z();
#pragma unroll
    for (int i = 0; i < 5; ++i) {
      l5a = f4fma(ST.l5_va[i], wv[i + 1], l5a);
      l5g = f4fma(ST.l5_g[i],  wv[i + 1], l5g);
    }
    float4 l7a = f4z(), l7g = f4z(), gb = f4z(), gc0 = f4z(), gca = f4z(), gsa = f4z();
#pragma unroll
    for (int i = 0; i < 7; ++i) {
      l7a = f4fma(ST.l7_va[i], wv[i], l7a);
      l7g = f4fma(ST.l7_g[i],  wv[i], l7g);
      gb  = f4fma(ST.v_gb[i],  wv[i], gb);
      gc0 = f4fma(ST.v_gc0[i], wv[i], gc0);
      gca = f4fma(ST.v_gca[i], wv[i], gca);
      gsa = f4fma(ST.v_gsa[i], wv[i], gsa);
    }
    const int o = r * TCOLS + c4;
    *(float4*)&T[T_B5][o]  = b5;
    *(float4*)&T[T_L5A][o] = l5a;
    *(float4*)&T[T_L5G][o] = l5g;
    *(float4*)&T[T_L7A][o] = l7a;
    *(float4*)&T[T_L7G][o] = l7g;
    *(float4*)&T[T_GB][o]  = gb;
    *(float4*)&T[T_GC0][o] = gc0;
    *(float4*)&T[T_GCA][o] = gca;
    *(float4*)&T[T_GSA][o] = gsa;
  }
  __syncthreads();

  // ---- stage B: horizontal passes, 4 px per thread ----
  const int toff = ty * TCOLS + 4 * tx;
  float w[12];
  float l7[4] = {}, l5[4] = {}, g0[4] = {}, g90[4] = {}, Pa[4] = {}, Qa[4] = {};
  float box[4];

  loadw12(&T[T_L7A][toff], w);           // rank 1: va (x) g
#pragma unroll
  for (int dx = 0; dx < 7; ++dx) {
    const float cc = ST.l7_g[dx];
#pragma unroll
    for (int c = 0; c < 4; ++c) l7[c] = fmaf(w[c + dx + 1], cc, l7[c]);
  }
  loadw12(&T[T_L7G][toff], w);           // rank 2: g (x) wb
#pragma unroll
  for (int dx = 0; dx < 7; ++dx) {
    const float cc = ST.l7_wb[dx];
#pragma unroll
    for (int c = 0; c < 4; ++c) l7[c] = fmaf(w[c + dx + 1], cc, l7[c]);
  }
  loadw12(&T[T_L5A][toff], w);
#pragma unroll
  for (int dx = 0; dx < 5; ++dx) {
    const float cc = ST.l5_g[dx];
#pragma unroll
    for (int c = 0; c < 4; ++c) l5[c] = fmaf(w[c + dx + 2], cc, l5[c]);
  }
  loadw12(&T[T_L5G][toff], w);
#pragma unroll
  for (int dx = 0; dx < 5; ++dx) {
    const float cc = ST.l5_wb[dx];
#pragma unroll
    for (int c = 0; c < 4; ++c) l5[c] = fmaf(w[c + dx + 2], cc, l5[c]);
  }
  loadw12(&T[T_B5][toff], w);
#pragma unroll
  for (int c = 0; c < 4; ++c)
    box[c] = ((w[c + 2] + w[c + 3]) + (w[c + 4] + w[c + 5])) + w[c + 6];
  loadw12(&T[T_GB][toff], w);
#pragma unroll
  for (int dx = 0; dx < 7; ++dx) {
    const float cc = ST.h_g0[dx];
#pragma unroll
    for (int c = 0; c < 4; ++c) g0[c] = fmaf(w[c + dx + 1], cc, g0[c]);
  }
  loadw12(&T[T_GC0][toff], w);
#pragma unroll
  for (int dx = 0; dx < 7; ++dx) {
    const float cc = ST.h_g90[dx];
#pragma unroll
    for (int c = 0; c < 4; ++c) g90[c] = fmaf(w[c + dx + 1], cc, g90[c]);
  }
  loadw12(&T[T_GCA][toff], w);
#pragma unroll
  for (int dx = 0; dx < 7; ++dx) {
    const float cc = ST.h_gc[dx];
#pragma unroll
    for (int c = 0; c < 4; ++c) Pa[c] = fmaf(w[c + dx + 1], cc, Pa[c]);
  }
  loadw12(&T[T_GSA][toff], w);
#pragma unroll
  for (int dx = 0; dx < 7; ++dx) {
    const float cc = ST.h_gs[dx];
#pragma unroll
    for (int c = 0; c < 4; ++c) Qa[c] = fmaf(w[c + dx + 1], cc, Qa[c]);
  }

  // ---- 3x3 filters direct from input tile via symmetry class sums ----
  float tr[12], mr[12], br[12];
  loadw12(&tile[(ty + 2) * LDSW + 4 * tx], tr);
  loadw12(&tile[(ty + 3) * LDSW + 4 * tx], mr);
  loadw12(&tile[(ty + 4) * LDSW + 4 * tx], br);

  // ---- epilogue: max commutes with monotone tanh/squash; store ----
  const int X = x0 + 4 * tx;
  const int yo = y0 + ty;
  const size_t fs = (size_t)planes * (IMG_H * IMG_W);
  const size_t off = (size_t)plane * (IMG_H * IMG_W) + (size_t)yo * IMG_W + X;

  *(float4*)(out + off) = make_float4(mr[4], mr[5], mr[6], mr[7]);  // original

  float lp[4], lo[4], ho[4], go[4];
#pragma unroll
  for (int c = 0; c < 4; ++c) {
    const float mC = mr[c + 4];
    const float e  = (tr[c + 4] + br[c + 4]) + (mr[c + 3] + mr[c + 5]);
    const float sC = (tr[c + 3] + tr[c + 5]) + (br[c + 3] + br[c + 5]);
    lp[c] = fmaf(0.25f, mC, fmaf(0.125f, e, 0.0625f * sC));          // lpf
    const float l3v = fmaf(ST.l3_m, mC, fmaf(ST.l3_e, e, ST.l3_s * sC));
    const float h3v = fmaf(8.f, mC, -(e + sC));                      // hpf3
    const float h5v = fmaf(25.f, mC, -box[c]);                       // hpf5
    lo[c] = squash_from(fmaxf(fmaxf(l3v, l5[c]), l7[c]));
    ho[c] = squash_from(fmaxf(h3v, h5v));
    const float o45  = (Pa[c] - Qa[c]) * ST.is45;
    const float o135 = (Pa[c] + Qa[c]) * ST.is135;
    go[c] = fast_tanh(0.1f * fmaxf(fmaxf(g0[c], g90[c]), fmaxf(o45, o135)));
  }
  *(float4*)(out + fs + off) = make_float4(lp[0], lp[1], lp[2], lp[3]);
  *(float4*)(out + 2 * fs + off) = make_float4(lo[0], lo[1], lo[2], lo[3]);
  *(float4*)(out + 3 * fs + off) = make_float4(ho[0], ho[1], ho[2], ho[3]);
  if (do_gab)
    *(float4*)(out + 4 * fs + off) = make_float4(go[0], go[1], go[2], go[3]);
}

extern "C" void kernel_launch(void* const* d_in, const int* in_sizes, int n_in,
                              void* d_out, int out_size, void* d_ws, size_t ws_size,
                              hipStream_t stream) {
  const float* x = (const float*)d_in[0];
  float* out = (float*)d_out;
  const int plane_elems = IMG_H * IMG_W;
  const int planes = in_sizes[0] / plane_elems;               // 16*3 = 48
  const int do_gab = (out_size >= 5 * in_sizes[0]) ? 1 : 0;

  dim3 grid(IMG_W / TILE_W, IMG_H / TILE_H, planes);
  msif_kernel<<<grid, NTHREADS, 0, stream>>>(x, out, planes, do_gab);
}